// Round 1
// baseline (40018.768 us; speedup 1.0000x reference)
//
#include <hip/hip_runtime.h>
#include <math.h>

#define Bq 4
#define Tq 2048
#define Cq 1024
#define Hq 16
#define Nq 64

__device__ inline float waveSum(float v) {
#pragma unroll
  for (int o = 32; o; o >>= 1) v += __shfl_xor(v, o);
  return v;
}
__device__ inline float waveMax(float v) {
#pragma unroll
  for (int o = 32; o; o >>= 1) v = fmaxf(v, __shfl_xor(v, o));
  return v;
}

// C[m][j] = sum_k A[m][k] * W[j][k]
// mode 1: store transposed (B,H,T,N)
// mode 2: transposed + v-mix with v1/lamb
// mode 3: plain (B,T,C) + residual add
__global__ __launch_bounds__(256) void gemm_nt(
    const float* __restrict__ A, const float* __restrict__ W,
    float* __restrict__ dst, const float* __restrict__ extra,
    const float* __restrict__ lamb_p, int mode)
{
  const int K = Cq;
  const int m0 = blockIdx.x * 64, j0 = blockIdx.y * 64;
  __shared__ float As[16][65];
  __shared__ float Bs[16][65];
  const int tid = threadIdx.x;
  const int tx = tid & 15, ty = tid >> 4;
  float acc[4][4] = {{0.f}};
  for (int k0 = 0; k0 < K; k0 += 16) {
#pragma unroll
    for (int i = 0; i < 4; ++i) {
      int idx = tid + i * 256;
      int mm = idx >> 4, kk = idx & 15;
      As[kk][mm] = A[(size_t)(m0 + mm) * K + k0 + kk];
      Bs[kk][mm] = W[(size_t)(j0 + mm) * K + k0 + kk];
    }
    __syncthreads();
#pragma unroll
    for (int k = 0; k < 16; ++k) {
      float a4[4], b4[4];
#pragma unroll
      for (int i = 0; i < 4; ++i) a4[i] = As[k][ty * 4 + i];
#pragma unroll
      for (int j = 0; j < 4; ++j) b4[j] = Bs[k][tx * 4 + j];
#pragma unroll
      for (int i = 0; i < 4; ++i)
#pragma unroll
        for (int j = 0; j < 4; ++j) acc[i][j] += a4[i] * b4[j];
    }
    __syncthreads();
  }
  const float lam = (mode == 2) ? lamb_p[0] : 0.0f;
#pragma unroll
  for (int i = 0; i < 4; ++i) {
    int m = m0 + ty * 4 + i;
#pragma unroll
    for (int j = 0; j < 4; ++j) {
      int jj = j0 + tx * 4 + j;
      float v = acc[i][j];
      if (mode == 3) {
        dst[(size_t)m * Cq + jj] = v + extra[(size_t)m * Cq + jj];
      } else {
        if (mode == 2) v = (1.0f - lam) * v + lam * extra[(size_t)m * Cq + jj];
        int b = m >> 11, t = m & (Tq - 1);
        int h = jj >> 6, n = jj & 63;
        dst[((((size_t)b * Hq + h) * Tq + t) << 6) | n] = v;
      }
    }
  }
}

// LN (optional) + token-shift blend + RoPE (optional). src/dst in (B,H,T,N).
__global__ __launch_bounds__(256) void postproc(
    const float* __restrict__ src, float* __restrict__ dst,
    const float* __restrict__ lnw, const float* __restrict__ lnb,
    const float* __restrict__ xs_p, int doLNRope)
{
  const int w = threadIdx.x >> 6, lane = threadIdx.x & 63;
  const int row = blockIdx.x * 4 + w;
  const int t = row & (Tq - 1);
  const int h = (row >> 11) & (Hq - 1);
  const size_t base = (size_t)row << 6;
  const size_t pbase = (t > 0) ? base - 64 : base;
  float cur = src[base + lane];
  float prv = src[pbase + lane];
  if (doLNRope) {
    const float lw = lnw[lane], lb = lnb[lane];
    {
      float m = waveSum(cur) * (1.0f / 64.0f);
      float d = cur - m;
      float var = waveSum(d * d) * (1.0f / 64.0f);
      cur = d * rsqrtf(var + 1e-5f) * lw + lb;
    }
    {
      float m = waveSum(prv) * (1.0f / 64.0f);
      float d = prv - m;
      float var = waveSum(d * d) * (1.0f / 64.0f);
      prv = d * rsqrtf(var + 1e-5f) * lw + lb;
    }
  }
  const float xv = xs_p[h * 64 + lane];
  float val = cur + xv * (prv - cur);
  if (doLNRope) {
    float partner = __shfl_xor(val, 1);
    if (lane < 32) {
      int i = lane >> 1;
      float freq = (float)exp((double)i * (-log(10000.0) / 15.0));
      float th = (float)t * freq;
      float c = cosf(th), s = sinf(th);
      val = c * val + ((lane & 1) ? -s : s) * partner;
    }
  }
  dst[base + lane] = val;
}

__global__ __launch_bounds__(256) void kw_kernel(
    const float* __restrict__ x, const float* __restrict__ Wkw, float* __restrict__ out)
{
  const int bt = blockIdx.x;
  const int tid = threadIdx.x, w = tid >> 6, lane = tid & 63;
  __shared__ float xs[Cq];
  for (int i = tid; i < Cq; i += 256) xs[i] = x[(size_t)bt * Cq + i];
  __syncthreads();
  const int b = bt >> 11, t = bt & (Tq - 1);
  for (int h = w; h < Hq; h += 4) {
    float acc = 0.0f;
    for (int i = lane; i < Cq; i += 64) acc += xs[i] * Wkw[h * Cq + i];
    acc = waveSum(acc);
    if (lane == 0) out[((size_t)(b * Hq + h)) * Tq + t] = 1.0f / (1.0f + expf(-acc));
  }
}

// One block per (b,h): sequential 8-chunk loop. 256 threads = 4 waves.
__global__ __launch_bounds__(256, 1) void attn_state_kernel(
    const float* __restrict__ qf, const float* __restrict__ kf, const float* __restrict__ vf,
    const float* __restrict__ kwp, float* __restrict__ y,
    float* __restrict__ dkg, float* __restrict__ dvg, float* __restrict__ dcg,
    const float* __restrict__ lnw, const float* __restrict__ lnb,
    const float* __restrict__ ftp, const float* __restrict__ stp)
{
  const int bh = blockIdx.x;
  const int h = bh & (Hq - 1);
  const int tid = threadIdx.x;
  const int w = tid >> 6, lane = tid & 63;

  const size_t seq = (size_t)Tq * Nq;
  const float* qb_ = qf + (size_t)bh * seq;
  const float* kb_ = kf + (size_t)bh * seq;
  const float* vb_ = vf + (size_t)bh * seq;
  const float* kwb = kwp + (size_t)bh * Tq;
  float* yb = y + (size_t)bh * seq;
  float* dkb = dkg + (size_t)bh * 256 * 64;
  float* dvb = dvg + (size_t)bh * 256 * 64;
  float* dcb = dcg + (size_t)bh * 256;

  const float ft = ftp[h], st = stp[h];
  const float lw = lnw[lane], lb = lnb[lane];
  const float scale = 0.125f;

  __shared__ float dkn[256][65];   // d_k_norm
  __shared__ float vst[256][65];   // v_state, later reused for ck0_ln
  __shared__ float pbuf[4][768];
  __shared__ float qsh[4][64];
  __shared__ float kwc_s[256];
  __shared__ int best_s[256];

  // zero per-(b,h) state
  for (int i = tid; i < 256 * 64; i += 256) { dkb[i] = 0.0f; dvb[i] = 0.0f; }
  dcb[tid] = 0.0f;
  __syncthreads();

  for (int c = 0; c < 8; ++c) {
    const int qb = c * 256;
    const int e = qb + 256;
    const int bb = (e - 512 > 0) ? (e - 512) : 0;
    const int L = e - bb;
    const int KS = 256 + L;

    // step 1: dkn = LN(d_k), vst = v_state
    for (int i = 0; i < 64; ++i) {
      int r = (w << 6) + i;
      float kd = dkb[r * 64 + lane];
      float mean = waveSum(kd) * (1.0f / 64.0f);
      float d0 = kd - mean;
      float var = waveSum(d0 * d0) * (1.0f / 64.0f);
      dkn[r][lane] = d0 * rsqrtf(var + 1e-5f) * lw + lb;
      float vd = dvb[r * 64 + lane];
      float nrm = fmaxf(sqrtf(waveSum(vd * vd)), 1e-12f);
      vst[r][lane] = vd / nrm * dcb[r];
    }
    __syncthreads();

    // step 2: attention, one wave per query row
    for (int r = w; r < 256; r += 4) {
      const int qi = qb + r;
      qsh[w][lane] = qb_[(size_t)qi * 64 + lane];
      float lmax = -3.0e38f;
      for (int j = lane; j < KS; j += 64) {
        float sc;
        if (j < 256) {
          float dot = 0.0f;
#pragma unroll 8
          for (int d = 0; d < 64; ++d) dot += qsh[w][d] * dkn[j][d];
          sc = st * scale * dot;
        } else {
          int kt = bb + (j - 256);
          if (kt <= qi) {
            const float* kr = kb_ + (size_t)kt * 64;
            float dot = 0.0f;
#pragma unroll 8
            for (int d = 0; d < 64; ++d) dot += qsh[w][d] * kr[d];
            sc = ft * scale * dot;
          } else sc = -1.0e30f;
        }
        pbuf[w][j] = sc;
        lmax = fmaxf(lmax, sc);
      }
      lmax = waveMax(lmax);
      float lsum = 0.0f;
      for (int j = lane; j < KS; j += 64) {
        float p = expf(pbuf[w][j] - lmax);
        pbuf[w][j] = p;
        lsum += p;
      }
      lsum = waveSum(lsum);
      const float inv = 1.0f / lsum;
      float acc = 0.0f;
      for (int j = 0; j < 256; ++j) acc += pbuf[w][j] * vst[j][lane];
      for (int j2 = 0; j2 < L; ++j2)
        acc += pbuf[w][256 + j2] * vb_[(size_t)(bb + j2) * 64 + lane];
      yb[(size_t)qi * 64 + lane] = acc * inv;
    }
    __syncthreads();

    // step 3a: ck0 = LN(zero-first-32(c_k)) into vst (reuse)
    for (int i = 0; i < 64; ++i) {
      int rc = (w << 6) + i;
      int kt = bb + rc;
      float kv = (lane < 32) ? 0.0f : kb_[(size_t)kt * 64 + lane];
      float mean = waveSum(kv) * (1.0f / 64.0f);
      float d0 = kv - mean;
      float var = waveSum(d0 * d0) * (1.0f / 64.0f);
      vst[rc][lane] = d0 * rsqrtf(var + 1e-5f) * lw + lb;
      if (lane == 0) kwc_s[rc] = kwb[kt];
    }
    __syncthreads();

    // step 3b: argmax over state slots (first-index tie-break, sink excluded)
    for (int rc = w; rc < 256; rc += 4) {
      float bv = -3.0e38f;
      int bi = 1 << 30;
#pragma unroll
      for (int ss = 0; ss < 4; ++ss) {
        int s = lane + (ss << 6);
        float dot = 0.0f;
#pragma unroll 8
        for (int d = 0; d < 64; ++d) dot += vst[rc][d] * dkn[s][d];
        if (s < 1) dot = -1.0e30f;  // SINK
        if (dot > bv || (dot == bv && s < bi)) { bv = dot; bi = s; }
      }
#pragma unroll
      for (int o = 32; o; o >>= 1) {
        float ov = __shfl_xor(bv, o);
        int oi = __shfl_xor(bi, o);
        if (ov > bv || (ov == bv && oi < bi)) { bv = ov; bi = oi; }
      }
      if (lane == 0) best_s[rc] = bi;
    }
    __syncthreads();

    // step 3c: deterministic ownership scatter (thread s owns state slot s)
    {
      const int s = tid;
      int cadd = 0;
      for (int rc = 0; rc < 256; ++rc) {
        if (best_s[rc] == s) {
          const float kwv = kwc_s[rc];
          const float* vr = vb_ + (size_t)(bb + rc) * 64;
          for (int d = 0; d < 64; ++d) {
            dkb[s * 64 + d] += vst[rc][d] * kwv;
            dvb[s * 64 + d] += vr[d] * kwv;
          }
          cadd++;
        }
      }
      dcb[s] += (float)cadd;
    }
    __syncthreads();
  }
}

// LN over C=1024 per (b,t); gathers from (B,H,T,N), writes (B,T,C)
__global__ __launch_bounds__(256) void final_ln(
    const float* __restrict__ y, const float* __restrict__ lnw,
    const float* __restrict__ lnb, float* __restrict__ dst)
{
  const int bt = blockIdx.x;
  const int b = bt >> 11, t = bt & (Tq - 1);
  const int tid = threadIdx.x, w = tid >> 6, lane = tid & 63;
  __shared__ float red[8];
  float v[4];
  float s = 0.0f;
#pragma unroll
  for (int i = 0; i < 4; ++i) {
    int c = tid + (i << 8);
    int h = c >> 6, n = c & 63;
    v[i] = y[((((size_t)b * Hq + h) * Tq + t) << 6) + n];
    s += v[i];
  }
  s = waveSum(s);
  if (lane == 0) red[w] = s;
  __syncthreads();
  const float mean = (red[0] + red[1] + red[2] + red[3]) * (1.0f / 1024.0f);
  float s2 = 0.0f;
#pragma unroll
  for (int i = 0; i < 4; ++i) { float d = v[i] - mean; s2 += d * d; }
  s2 = waveSum(s2);
  if (lane == 0) red[4 + w] = s2;
  __syncthreads();
  const float var = (red[4] + red[5] + red[6] + red[7]) * (1.0f / 1024.0f);
  const float rs = rsqrtf(var + 1e-5f);
#pragma unroll
  for (int i = 0; i < 4; ++i) {
    int c = tid + (i << 8);
    dst[(size_t)bt * Cq + c] = (v[i] - mean) * rs * lnw[c] + lnb[c];
  }
}

extern "C" void kernel_launch(void* const* d_in, const int* in_sizes, int n_in,
                              void* d_out, int out_size, void* d_ws, size_t ws_size,
                              hipStream_t stream)
{
  (void)in_sizes; (void)n_in; (void)out_size; (void)ws_size;
  const float* residual = (const float*)d_in[0];
  const float* x        = (const float*)d_in[1];
  const float* v1       = (const float*)d_in[2];
  const float* Wq       = (const float*)d_in[6];
  const float* Wk       = (const float*)d_in[7];
  const float* Wv       = (const float*)d_in[8];
  const float* Wproj    = (const float*)d_in[9];
  const float* Wkw      = (const float*)d_in[10];
  const float* x_q      = (const float*)d_in[11];
  const float* x_k      = (const float*)d_in[12];
  const float* x_v      = (const float*)d_in[13];
  const float* lamb     = (const float*)d_in[14];
  const float* ln_q_w   = (const float*)d_in[15];
  const float* ln_q_b   = (const float*)d_in[16];
  const float* ln_k_w   = (const float*)d_in[17];
  const float* ln_k_b   = (const float*)d_in[18];
  const float* ln_dk_w  = (const float*)d_in[19];
  const float* ln_dk_b  = (const float*)d_in[20];
  const float* ln_res_w = (const float*)d_in[21];
  const float* ln_res_b = (const float*)d_in[22];
  const float* ftp      = (const float*)d_in[23];
  const float* stp      = (const float*)d_in[24];

  float* ws = (float*)d_ws;
  const size_t SZ = (size_t)Bq * Hq * Tq * Nq;  // 8388608
  float* q_raw = ws;
  float* k_raw = ws + SZ;
  float* v_mix = ws + 2 * SZ;
  float* q_fin = ws + 3 * SZ;
  float* k_fin = ws + 4 * SZ;
  float* v_fin = ws + 5 * SZ;
  float* kwbuf = ws + 6 * SZ;                       // B*H*T
  float* dk = kwbuf + (size_t)Bq * Hq * Tq;         // B*H*256*64
  float* dv = dk + (size_t)Bq * Hq * 256 * 64;
  float* dc = dv + (size_t)Bq * Hq * 256 * 64;      // B*H*256
  float* ybuf = q_raw;   // q_raw dead after postproc
  float* ylnb = k_raw;   // k_raw dead after postproc

  dim3 gg(128, 16), gb(256);
  hipLaunchKernelGGL(gemm_nt, gg, gb, 0, stream, x, Wq, q_raw, (const float*)nullptr, lamb, 1);
  hipLaunchKernelGGL(gemm_nt, gg, gb, 0, stream, x, Wk, k_raw, (const float*)nullptr, lamb, 1);
  hipLaunchKernelGGL(gemm_nt, gg, gb, 0, stream, x, Wv, v_mix, v1, lamb, 2);
  hipLaunchKernelGGL(kw_kernel, dim3(Bq * Tq), gb, 0, stream, x, Wkw, kwbuf);
  const int rows = Bq * Hq * Tq;
  hipLaunchKernelGGL(postproc, dim3(rows / 4), gb, 0, stream, q_raw, q_fin, ln_q_w, ln_q_b, x_q, 1);
  hipLaunchKernelGGL(postproc, dim3(rows / 4), gb, 0, stream, k_raw, k_fin, ln_k_w, ln_k_b, x_k, 1);
  hipLaunchKernelGGL(postproc, dim3(rows / 4), gb, 0, stream, v_mix, v_fin, (const float*)nullptr, (const float*)nullptr, x_v, 0);
  hipLaunchKernelGGL(attn_state_kernel, dim3(Bq * Hq), gb, 0, stream, q_fin, k_fin, v_fin, kwbuf,
                     ybuf, dk, dv, dc, ln_dk_w, ln_dk_b, ftp, stp);
  hipLaunchKernelGGL(final_ln, dim3(Bq * Tq), gb, 0, stream, ybuf, ln_res_w, ln_res_b, ylnb);
  hipLaunchKernelGGL(gemm_nt, gg, gb, 0, stream, ylnb, Wproj, (float*)d_out, residual, lamb, 3);
}

// Round 2
// 7076.083 us; speedup vs baseline: 5.6555x; 5.6555x over previous
//
#include <hip/hip_runtime.h>
#include <math.h>

#define Bq 4
#define Tq 2048
#define Cq 1024
#define Hq 16
#define Nq 64

__device__ inline float waveSum(float v) {
#pragma unroll
  for (int o = 32; o; o >>= 1) v += __shfl_xor(v, o);
  return v;
}

// C[m][j] = sum_k A[m][k] * W[j][k]
// mode 1: store transposed (B,H,T,N)
// mode 2: transposed + v-mix with v1/lamb
// mode 3: plain (B,T,C) + residual add
__global__ __launch_bounds__(256) void gemm_nt(
    const float* __restrict__ A, const float* __restrict__ W,
    float* __restrict__ dst, const float* __restrict__ extra,
    const float* __restrict__ lamb_p, int mode)
{
  const int K = Cq;
  const int m0 = blockIdx.x * 64, j0 = blockIdx.y * 64;
  __shared__ float As[16][65];
  __shared__ float Bs[16][65];
  const int tid = threadIdx.x;
  const int tx = tid & 15, ty = tid >> 4;
  float acc[4][4] = {{0.f}};
  for (int k0 = 0; k0 < K; k0 += 16) {
#pragma unroll
    for (int i = 0; i < 4; ++i) {
      int idx = tid + i * 256;
      int mm = idx >> 4, kk = idx & 15;
      As[kk][mm] = A[(size_t)(m0 + mm) * K + k0 + kk];
      Bs[kk][mm] = W[(size_t)(j0 + mm) * K + k0 + kk];
    }
    __syncthreads();
#pragma unroll
    for (int k = 0; k < 16; ++k) {
      float a4[4], b4[4];
#pragma unroll
      for (int i = 0; i < 4; ++i) a4[i] = As[k][ty * 4 + i];
#pragma unroll
      for (int j = 0; j < 4; ++j) b4[j] = Bs[k][tx * 4 + j];
#pragma unroll
      for (int i = 0; i < 4; ++i)
#pragma unroll
        for (int j = 0; j < 4; ++j) acc[i][j] += a4[i] * b4[j];
    }
    __syncthreads();
  }
  const float lam = (mode == 2) ? lamb_p[0] : 0.0f;
#pragma unroll
  for (int i = 0; i < 4; ++i) {
    int m = m0 + ty * 4 + i;
#pragma unroll
    for (int j = 0; j < 4; ++j) {
      int jj = j0 + tx * 4 + j;
      float v = acc[i][j];
      if (mode == 3) {
        dst[(size_t)m * Cq + jj] = v + extra[(size_t)m * Cq + jj];
      } else {
        if (mode == 2) v = (1.0f - lam) * v + lam * extra[(size_t)m * Cq + jj];
        int b = m >> 11, t = m & (Tq - 1);
        int h = jj >> 6, n = jj & 63;
        dst[((((size_t)b * Hq + h) * Tq + t) << 6) | n] = v;
      }
    }
  }
}

// LN (optional) + token-shift blend + RoPE (optional). src/dst in (B,H,T,N).
__global__ __launch_bounds__(256) void postproc(
    const float* __restrict__ src, float* __restrict__ dst,
    const float* __restrict__ lnw, const float* __restrict__ lnb,
    const float* __restrict__ xs_p, int doLNRope)
{
  const int w = threadIdx.x >> 6, lane = threadIdx.x & 63;
  const int row = blockIdx.x * 4 + w;
  const int t = row & (Tq - 1);
  const int h = (row >> 11) & (Hq - 1);
  const size_t base = (size_t)row << 6;
  const size_t pbase = (t > 0) ? base - 64 : base;
  float cur = src[base + lane];
  float prv = src[pbase + lane];
  if (doLNRope) {
    const float lw = lnw[lane], lb = lnb[lane];
    {
      float m = waveSum(cur) * (1.0f / 64.0f);
      float d = cur - m;
      float var = waveSum(d * d) * (1.0f / 64.0f);
      cur = d * rsqrtf(var + 1e-5f) * lw + lb;
    }
    {
      float m = waveSum(prv) * (1.0f / 64.0f);
      float d = prv - m;
      float var = waveSum(d * d) * (1.0f / 64.0f);
      prv = d * rsqrtf(var + 1e-5f) * lw + lb;
    }
  }
  const float xv = xs_p[h * 64 + lane];
  float val = cur + xv * (prv - cur);
  if (doLNRope) {
    float partner = __shfl_xor(val, 1);
    if (lane < 32) {
      int i = lane >> 1;
      float freq = (float)exp((double)i * (-log(10000.0) / 15.0));
      float th = (float)t * freq;
      float c = cosf(th), s = sinf(th);
      val = c * val + ((lane & 1) ? -s : s) * partner;
    }
  }
  dst[base + lane] = val;
}

__global__ __launch_bounds__(256) void kw_kernel(
    const float* __restrict__ x, const float* __restrict__ Wkw, float* __restrict__ out)
{
  const int bt = blockIdx.x;
  const int tid = threadIdx.x, w = tid >> 6, lane = tid & 63;
  __shared__ float xs[Cq];
  for (int i = tid; i < Cq; i += 256) xs[i] = x[(size_t)bt * Cq + i];
  __syncthreads();
  const int b = bt >> 11, t = bt & (Tq - 1);
  for (int h = w; h < Hq; h += 4) {
    float acc = 0.0f;
    for (int i = lane; i < Cq; i += 64) acc += xs[i] * Wkw[h * Cq + i];
    acc = waveSum(acc);
    if (lane == 0) out[((size_t)(b * Hq + h)) * Tq + t] = 1.0f / (1.0f + expf(-acc));
  }
}

// Phase A: sequential state evolution per (b,h); writes per-chunk snapshots.
// 64 blocks x 512 threads (8 waves).
__global__ __launch_bounds__(512, 1) void state_evolve_kernel(
    const float* __restrict__ kf, const float* __restrict__ vf,
    const float* __restrict__ kwp,
    float* __restrict__ dkg, float* __restrict__ dvg, float* __restrict__ dcg,
    float* __restrict__ dkn_snap, float* __restrict__ vst_snap,
    const float* __restrict__ lnw, const float* __restrict__ lnb)
{
  const int bh = blockIdx.x;
  const int tid = threadIdx.x;
  const int w = tid >> 6, lane = tid & 63;
  const size_t seq = (size_t)Tq * Nq;
  const float* kb_ = kf + (size_t)bh * seq;
  const float* vb_ = vf + (size_t)bh * seq;
  const float* kwb = kwp + (size_t)bh * Tq;
  float* dkb = dkg + (size_t)bh * (256 * 64);
  float* dvb = dvg + (size_t)bh * (256 * 64);
  float* dcb = dcg + (size_t)bh * 256;
  float* dksn = dkn_snap + (size_t)bh * 8 * 16384;
  float* vssn = vst_snap + (size_t)bh * 8 * 16384;
  const float lw = lnw[lane], lb = lnb[lane];

  __shared__ float dkn[256][68];
  __shared__ float ck0[256][68];
  __shared__ float kwc_s[256];
  __shared__ int best_s[256];

  for (int i = tid; i < 256 * 64; i += 512) { dkb[i] = 0.0f; dvb[i] = 0.0f; }
  if (tid < 256) dcb[tid] = 0.0f;
  __syncthreads();

  for (int c = 0; c < 8; ++c) {
    const int e = c * 256 + 256;
    const int bb = (e - 512 > 0) ? (e - 512) : 0;

    // step 1: dkn = LN(d_k) (LDS + snapshot); v_state -> snapshot
    for (int i = 0; i < 32; ++i) {
      int r = w * 32 + i;
      float kd = dkb[r * 64 + lane];
      float mean = waveSum(kd) * (1.0f / 64.0f);
      float d0 = kd - mean;
      float var = waveSum(d0 * d0) * (1.0f / 64.0f);
      float kn = d0 * rsqrtf(var + 1e-5f) * lw + lb;
      dkn[r][lane] = kn;
      dksn[(size_t)c * 16384 + r * 64 + lane] = kn;
      float vd = dvb[r * 64 + lane];
      float nrm = fmaxf(sqrtf(waveSum(vd * vd)), 1e-12f);
      vssn[(size_t)c * 16384 + r * 64 + lane] = vd / nrm * dcb[r];
    }
    // step 2: ck0 = LN(zero-first-32(c_k))
    for (int i = 0; i < 32; ++i) {
      int rc = w * 32 + i;
      int kt = bb + rc;
      float kv = (lane < 32) ? 0.0f : kb_[(size_t)kt * 64 + lane];
      float mean = waveSum(kv) * (1.0f / 64.0f);
      float d0 = kv - mean;
      float var = waveSum(d0 * d0) * (1.0f / 64.0f);
      ck0[rc][lane] = d0 * rsqrtf(var + 1e-5f) * lw + lb;
      if (lane == 0) kwc_s[rc] = kwb[kt];
    }
    __syncthreads();

    // step 3: argmax over 256 slots (first-index tie-break, sink excluded)
    for (int i = 0; i < 32; ++i) {
      int rc = w * 32 + i;
      float bv = -3.0e38f;
      int bi = 1 << 30;
#pragma unroll
      for (int ss = 0; ss < 4; ++ss) {
        int s = lane + (ss << 6);
        const float* dr = &dkn[s][0];
        const float* cr = &ck0[rc][0];
        float dot = 0.0f;
#pragma unroll
        for (int d4 = 0; d4 < 16; ++d4) {
          float4 a = *(const float4*)(cr + d4 * 4);
          float4 b = *(const float4*)(dr + d4 * 4);
          dot += a.x * b.x + a.y * b.y + a.z * b.z + a.w * b.w;
        }
        if (s < 1) dot = -1.0e30f;  // SINK
        if (dot > bv || (dot == bv && s < bi)) { bv = dot; bi = s; }
      }
#pragma unroll
      for (int o = 32; o; o >>= 1) {
        float ov = __shfl_xor(bv, o);
        int oi = __shfl_xor(bi, o);
        if (ov > bv || (ov == bv && oi < bi)) { bv = ov; bi = oi; }
      }
      if (lane == 0) best_s[rc] = bi;
    }
    __syncthreads();

    // step 4: ownership scatter (thread s owns slot s), global RMW
    if (tid < 256) {
      const int s = tid;
      int cadd = 0;
      float* dkr = dkb + s * 64;
      float* dvr = dvb + s * 64;
      for (int rc = 0; rc < 256; ++rc) {
        if (best_s[rc] == s) {
          const float kwv = kwc_s[rc];
          const float* vr = vb_ + (size_t)(bb + rc) * 64;
          const float* cr = &ck0[rc][0];
#pragma unroll
          for (int d4 = 0; d4 < 16; ++d4) {
            float4 cv = *(const float4*)(cr + d4 * 4);
            float4 dk4 = *(float4*)(dkr + d4 * 4);
            dk4.x += cv.x * kwv; dk4.y += cv.y * kwv;
            dk4.z += cv.z * kwv; dk4.w += cv.w * kwv;
            *(float4*)(dkr + d4 * 4) = dk4;
            float4 vv = *(const float4*)(vr + d4 * 4);
            float4 dv4 = *(float4*)(dvr + d4 * 4);
            dv4.x += vv.x * kwv; dv4.y += vv.y * kwv;
            dv4.z += vv.z * kwv; dv4.w += vv.w * kwv;
            *(float4*)(dvr + d4 * 4) = dv4;
          }
          cadd++;
        }
      }
      dcb[s] += (float)cadd;
    }
    __syncthreads();
  }
}

// Phase B: parallel attention. Grid 512 = (bh, chunk); thread owns one q-row.
__global__ __launch_bounds__(256) void attn_apply_kernel(
    const float* __restrict__ qf, const float* __restrict__ kfin,
    const float* __restrict__ vfin, const float* __restrict__ dkn_snap,
    const float* __restrict__ vst_snap, float* __restrict__ y,
    const float* __restrict__ ftp, const float* __restrict__ stp)
{
  const int blk = blockIdx.x;
  const int bh = blk >> 3;
  const int c = blk & 7;
  const int h = bh & (Hq - 1);
  const int tid = threadIdx.x;
  const size_t seq = (size_t)Tq * Nq;
  const int qi = c * 256 + tid;
  const int e = c * 256 + 256;
  const int bb = (e - 512 > 0) ? (e - 512) : 0;
  const int L = e - bb;
  const int ntile = 4 + (L >> 6);
  const float stsc = stp[h] * 0.125f, ftsc = ftp[h] * 0.125f;

  __shared__ float Ks[4096];
  __shared__ float Vs[4096];

  float q[64], o[64];
  {
    const float* qrow = qf + (size_t)bh * seq + (size_t)qi * 64;
#pragma unroll
    for (int d4 = 0; d4 < 16; ++d4) {
      float4 t = *(const float4*)(qrow + d4 * 4);
      q[4 * d4 + 0] = t.x; q[4 * d4 + 1] = t.y;
      q[4 * d4 + 2] = t.z; q[4 * d4 + 3] = t.w;
      o[4 * d4 + 0] = 0.f; o[4 * d4 + 1] = 0.f;
      o[4 * d4 + 2] = 0.f; o[4 * d4 + 3] = 0.f;
    }
  }
  float m = -3.0e38f, l = 0.0f;

  const float* kwin = kfin + (size_t)bh * seq;
  const float* vwin = vfin + (size_t)bh * seq;
  const float* dks = dkn_snap + ((size_t)(bh * 8 + c)) * 16384;
  const float* vss = vst_snap + ((size_t)(bh * 8 + c)) * 16384;

  for (int tt = 0; tt < ntile; ++tt) {
    const float* ksrc; const float* vsrc;
    int kt0 = 0;
    if (tt < 4) {
      ksrc = dks + tt * 4096;
      vsrc = vss + tt * 4096;
    } else {
      kt0 = bb + ((tt - 4) << 6);
      ksrc = kwin + (size_t)kt0 * 64;
      vsrc = vwin + (size_t)kt0 * 64;
    }
    __syncthreads();
#pragma unroll
    for (int i = 0; i < 4; ++i) {
      ((float4*)Ks)[i * 256 + tid] = ((const float4*)ksrc)[i * 256 + tid];
      ((float4*)Vs)[i * 256 + tid] = ((const float4*)vsrc)[i * 256 + tid];
    }
    __syncthreads();
    const float scale = (tt < 4) ? stsc : ftsc;
    int jmax = 64;
    if (tt >= 4) {
      int lim = qi - kt0 + 1;
      jmax = lim < 0 ? 0 : (lim > 64 ? 64 : lim);
    }
    for (int j = 0; j < jmax; ++j) {
      const float* kr = Ks + j * 64;
      float s = 0.0f;
#pragma unroll
      for (int d4 = 0; d4 < 16; ++d4) {
        float4 kv = *(const float4*)(kr + d4 * 4);
        s += q[4 * d4 + 0] * kv.x + q[4 * d4 + 1] * kv.y +
             q[4 * d4 + 2] * kv.z + q[4 * d4 + 3] * kv.w;
      }
      s *= scale;
      const float* vr = Vs + j * 64;
      if (s > m) {
        float al = __expf(m - s);
        m = s;
        l = l * al + 1.0f;
#pragma unroll
        for (int d4 = 0; d4 < 16; ++d4) {
          float4 vv = *(const float4*)(vr + d4 * 4);
          o[4 * d4 + 0] = o[4 * d4 + 0] * al + vv.x;
          o[4 * d4 + 1] = o[4 * d4 + 1] * al + vv.y;
          o[4 * d4 + 2] = o[4 * d4 + 2] * al + vv.z;
          o[4 * d4 + 3] = o[4 * d4 + 3] * al + vv.w;
        }
      } else {
        float p = __expf(s - m);
        l += p;
#pragma unroll
        for (int d4 = 0; d4 < 16; ++d4) {
          float4 vv = *(const float4*)(vr + d4 * 4);
          o[4 * d4 + 0] += p * vv.x;
          o[4 * d4 + 1] += p * vv.y;
          o[4 * d4 + 2] += p * vv.z;
          o[4 * d4 + 3] += p * vv.w;
        }
      }
    }
  }
  const float inv = 1.0f / l;
  float* yb = y + (size_t)bh * seq + (size_t)qi * 64;
#pragma unroll
  for (int d4 = 0; d4 < 16; ++d4) {
    float4 st4 = make_float4(o[4 * d4 + 0] * inv, o[4 * d4 + 1] * inv,
                             o[4 * d4 + 2] * inv, o[4 * d4 + 3] * inv);
    *(float4*)(yb + d4 * 4) = st4;
  }
}

// LN over C=1024 per (b,t); gathers from (B,H,T,N), writes (B,T,C)
__global__ __launch_bounds__(256) void final_ln(
    const float* __restrict__ y, const float* __restrict__ lnw,
    const float* __restrict__ lnb, float* __restrict__ dst)
{
  const int bt = blockIdx.x;
  const int b = bt >> 11, t = bt & (Tq - 1);
  const int tid = threadIdx.x, w = tid >> 6, lane = tid & 63;
  __shared__ float red[8];
  float v[4];
  float s = 0.0f;
#pragma unroll
  for (int i = 0; i < 4; ++i) {
    int c = tid + (i << 8);
    int h = c >> 6, n = c & 63;
    v[i] = y[((((size_t)b * Hq + h) * Tq + t) << 6) + n];
    s += v[i];
  }
  s = waveSum(s);
  if (lane == 0) red[w] = s;
  __syncthreads();
  const float mean = (red[0] + red[1] + red[2] + red[3]) * (1.0f / 1024.0f);
  float s2 = 0.0f;
#pragma unroll
  for (int i = 0; i < 4; ++i) { float d = v[i] - mean; s2 += d * d; }
  s2 = waveSum(s2);
  if (lane == 0) red[4 + w] = s2;
  __syncthreads();
  const float var = (red[4] + red[5] + red[6] + red[7]) * (1.0f / 1024.0f);
  const float rs = rsqrtf(var + 1e-5f);
#pragma unroll
  for (int i = 0; i < 4; ++i) {
    int c = tid + (i << 8);
    dst[(size_t)bt * Cq + c] = (v[i] - mean) * rs * lnw[c] + lnb[c];
  }
}

extern "C" void kernel_launch(void* const* d_in, const int* in_sizes, int n_in,
                              void* d_out, int out_size, void* d_ws, size_t ws_size,
                              hipStream_t stream)
{
  (void)in_sizes; (void)n_in; (void)out_size; (void)ws_size;
  const float* residual = (const float*)d_in[0];
  const float* x        = (const float*)d_in[1];
  const float* v1       = (const float*)d_in[2];
  const float* Wq       = (const float*)d_in[6];
  const float* Wk       = (const float*)d_in[7];
  const float* Wv       = (const float*)d_in[8];
  const float* Wproj    = (const float*)d_in[9];
  const float* Wkw      = (const float*)d_in[10];
  const float* x_q      = (const float*)d_in[11];
  const float* x_k      = (const float*)d_in[12];
  const float* x_v      = (const float*)d_in[13];
  const float* lamb     = (const float*)d_in[14];
  const float* ln_q_w   = (const float*)d_in[15];
  const float* ln_q_b   = (const float*)d_in[16];
  const float* ln_k_w   = (const float*)d_in[17];
  const float* ln_k_b   = (const float*)d_in[18];
  const float* ln_dk_w  = (const float*)d_in[19];
  const float* ln_dk_b  = (const float*)d_in[20];
  const float* ln_res_w = (const float*)d_in[21];
  const float* ln_res_b = (const float*)d_in[22];
  const float* ftp      = (const float*)d_in[23];
  const float* stp      = (const float*)d_in[24];

  float* ws = (float*)d_ws;
  const size_t SZ = (size_t)Bq * Hq * Tq * Nq;  // 8388608
  float* q_raw = ws;
  float* k_raw = ws + SZ;
  float* v_mix = ws + 2 * SZ;
  float* q_fin = ws + 3 * SZ;
  float* k_fin = ws + 4 * SZ;
  float* v_fin = ws + 5 * SZ;
  float* kwbuf = ws + 6 * SZ;                       // B*H*T = 131072
  float* dk = kwbuf + (size_t)Bq * Hq * Tq;         // 64*16384
  float* dv = dk + (size_t)Bq * Hq * 256 * 64;
  float* dc = dv + (size_t)Bq * Hq * 256 * 64;      // 64*256
  // snapshots reuse q_raw/k_raw (dead after postproc); 64*8*16384 == SZ exactly
  float* dkn_snap = q_raw;
  float* vst_snap = k_raw;
  float* ybuf = v_mix;   // v_mix dead after postproc
  float* ylnb = q_raw;   // dkn_snap dead after attn_apply

  dim3 gg(128, 16), gb(256);
  hipLaunchKernelGGL(gemm_nt, gg, gb, 0, stream, x, Wq, q_raw, (const float*)nullptr, lamb, 1);
  hipLaunchKernelGGL(gemm_nt, gg, gb, 0, stream, x, Wk, k_raw, (const float*)nullptr, lamb, 1);
  hipLaunchKernelGGL(gemm_nt, gg, gb, 0, stream, x, Wv, v_mix, v1, lamb, 2);
  hipLaunchKernelGGL(kw_kernel, dim3(Bq * Tq), gb, 0, stream, x, Wkw, kwbuf);
  const int rows = Bq * Hq * Tq;
  hipLaunchKernelGGL(postproc, dim3(rows / 4), gb, 0, stream, q_raw, q_fin, ln_q_w, ln_q_b, x_q, 1);
  hipLaunchKernelGGL(postproc, dim3(rows / 4), gb, 0, stream, k_raw, k_fin, ln_k_w, ln_k_b, x_k, 1);
  hipLaunchKernelGGL(postproc, dim3(rows / 4), gb, 0, stream, v_mix, v_fin, (const float*)nullptr, (const float*)nullptr, x_v, 0);
  hipLaunchKernelGGL(state_evolve_kernel, dim3(Bq * Hq), dim3(512), 0, stream,
                     k_fin, v_fin, kwbuf, dk, dv, dc, dkn_snap, vst_snap, ln_dk_w, ln_dk_b);
  hipLaunchKernelGGL(attn_apply_kernel, dim3(Bq * Hq * 8), gb, 0, stream,
                     q_fin, k_fin, v_fin, dkn_snap, vst_snap, ybuf, ftp, stp);
  hipLaunchKernelGGL(final_ln, dim3(Bq * Tq), gb, 0, stream, ybuf, ln_res_w, ln_res_b, ylnb);
  hipLaunchKernelGGL(gemm_nt, gg, gb, 0, stream, ylnb, Wproj, (float*)d_out, residual, lamb, 3);
}

// Round 3
// 3691.287 us; speedup vs baseline: 10.8414x; 1.9170x over previous
//
#include <hip/hip_runtime.h>
#include <math.h>

#define Bq 4
#define Tq 2048
#define Cq 1024
#define Hq 16
#define Nq 64

__device__ inline float waveSum(float v) {
#pragma unroll
  for (int o = 32; o; o >>= 1) v += __shfl_xor(v, o);
  return v;
}

// C[m][j] = sum_k A[m][k] * W[j][k]
// mode 1: store transposed (B,H,T,N)
// mode 2: transposed + v-mix with v1/lamb
// mode 3: plain (B,T,C) + residual add
__global__ __launch_bounds__(256) void gemm_nt(
    const float* __restrict__ A, const float* __restrict__ W,
    float* __restrict__ dst, const float* __restrict__ extra,
    const float* __restrict__ lamb_p, int mode)
{
  const int K = Cq;
  const int m0 = blockIdx.x * 64, j0 = blockIdx.y * 64;
  __shared__ float As[16][65];
  __shared__ float Bs[16][65];
  const int tid = threadIdx.x;
  const int tx = tid & 15, ty = tid >> 4;
  float acc[4][4] = {{0.f}};
  for (int k0 = 0; k0 < K; k0 += 16) {
#pragma unroll
    for (int i = 0; i < 4; ++i) {
      int idx = tid + i * 256;
      int mm = idx >> 4, kk = idx & 15;
      As[kk][mm] = A[(size_t)(m0 + mm) * K + k0 + kk];
      Bs[kk][mm] = W[(size_t)(j0 + mm) * K + k0 + kk];
    }
    __syncthreads();
#pragma unroll
    for (int k = 0; k < 16; ++k) {
      float a4[4], b4[4];
#pragma unroll
      for (int i = 0; i < 4; ++i) a4[i] = As[k][ty * 4 + i];
#pragma unroll
      for (int j = 0; j < 4; ++j) b4[j] = Bs[k][tx * 4 + j];
#pragma unroll
      for (int i = 0; i < 4; ++i)
#pragma unroll
        for (int j = 0; j < 4; ++j) acc[i][j] += a4[i] * b4[j];
    }
    __syncthreads();
  }
  const float lam = (mode == 2) ? lamb_p[0] : 0.0f;
#pragma unroll
  for (int i = 0; i < 4; ++i) {
    int m = m0 + ty * 4 + i;
#pragma unroll
    for (int j = 0; j < 4; ++j) {
      int jj = j0 + tx * 4 + j;
      float v = acc[i][j];
      if (mode == 3) {
        dst[(size_t)m * Cq + jj] = v + extra[(size_t)m * Cq + jj];
      } else {
        if (mode == 2) v = (1.0f - lam) * v + lam * extra[(size_t)m * Cq + jj];
        int b = m >> 11, t = m & (Tq - 1);
        int h = jj >> 6, n = jj & 63;
        dst[((((size_t)b * Hq + h) * Tq + t) << 6) | n] = v;
      }
    }
  }
}

// LN (optional) + token-shift blend + RoPE (optional). src/dst in (B,H,T,N).
__global__ __launch_bounds__(256) void postproc(
    const float* __restrict__ src, float* __restrict__ dst,
    const float* __restrict__ lnw, const float* __restrict__ lnb,
    const float* __restrict__ xs_p, int doLNRope)
{
  const int w = threadIdx.x >> 6, lane = threadIdx.x & 63;
  const int row = blockIdx.x * 4 + w;
  const int t = row & (Tq - 1);
  const int h = (row >> 11) & (Hq - 1);
  const size_t base = (size_t)row << 6;
  const size_t pbase = (t > 0) ? base - 64 : base;
  float cur = src[base + lane];
  float prv = src[pbase + lane];
  if (doLNRope) {
    const float lw = lnw[lane], lb = lnb[lane];
    {
      float m = waveSum(cur) * (1.0f / 64.0f);
      float d = cur - m;
      float var = waveSum(d * d) * (1.0f / 64.0f);
      cur = d * rsqrtf(var + 1e-5f) * lw + lb;
    }
    {
      float m = waveSum(prv) * (1.0f / 64.0f);
      float d = prv - m;
      float var = waveSum(d * d) * (1.0f / 64.0f);
      prv = d * rsqrtf(var + 1e-5f) * lw + lb;
    }
  }
  const float xv = xs_p[h * 64 + lane];
  float val = cur + xv * (prv - cur);
  if (doLNRope) {
    float partner = __shfl_xor(val, 1);
    if (lane < 32) {
      int i = lane >> 1;
      float freq = (float)exp((double)i * (-log(10000.0) / 15.0));
      float th = (float)t * freq;
      float c = cosf(th), s = sinf(th);
      val = c * val + ((lane & 1) ? -s : s) * partner;
    }
  }
  dst[base + lane] = val;
}

__global__ __launch_bounds__(256) void kw_kernel(
    const float* __restrict__ x, const float* __restrict__ Wkw, float* __restrict__ out)
{
  const int bt = blockIdx.x;
  const int tid = threadIdx.x, w = tid >> 6, lane = tid & 63;
  __shared__ float xs[Cq];
  for (int i = tid; i < Cq; i += 256) xs[i] = x[(size_t)bt * Cq + i];
  __syncthreads();
  const int b = bt >> 11, t = bt & (Tq - 1);
  for (int h = w; h < Hq; h += 4) {
    float acc = 0.0f;
    for (int i = lane; i < Cq; i += 64) acc += xs[i] * Wkw[h * Cq + i];
    acc = waveSum(acc);
    if (lane == 0) out[((size_t)(b * Hq + h)) * Tq + t] = 1.0f / (1.0f + expf(-acc));
  }
}

// Phase A: sequential state evolution per (b,h); writes per-chunk snapshots.
// 64 blocks x 512 threads. Transposed LDS + register-tiled sim + parallel scatter.
__global__ __launch_bounds__(512) void state_evolve_kernel(
    const float* __restrict__ kf, const float* __restrict__ vf,
    const float* __restrict__ kwp,
    float* __restrict__ dkg, float* __restrict__ dvg, float* __restrict__ dcg,
    float* __restrict__ dkn_snap, float* __restrict__ vst_snap,
    const float* __restrict__ lnw, const float* __restrict__ lnb)
{
  const int bh = blockIdx.x;
  const int tid = threadIdx.x;
  const int w = tid >> 6, lane = tid & 63;
  const size_t seq = (size_t)Tq * Nq;
  const float* kb_ = kf + (size_t)bh * seq;
  const float* vb_ = vf + (size_t)bh * seq;
  const float* kwb = kwp + (size_t)bh * Tq;
  float* dkb = dkg + (size_t)bh * (256 * 64);
  float* dvb = dvg + (size_t)bh * (256 * 64);
  float* dcb = dcg + (size_t)bh * 256;
  float* dksn = dkn_snap + (size_t)bh * 8 * 16384;
  float* vssn = vst_snap + (size_t)bh * 8 * 16384;
  const float lw = lnw[lane], lb = lnb[lane];

  // k-major transposed tiles; stride 260 keeps float4 16B-aligned, 2-bank row shift
  __shared__ float dknT[64][260];  // [k][slot]; reused as vT[d][rc] in scatter
  __shared__ float ck0T[64][260];  // [k][rc]
  __shared__ float kwc_s[256];
  __shared__ int best_s[256];

  for (int i = tid; i < 256 * 64; i += 512) { dkb[i] = 0.0f; dvb[i] = 0.0f; }
  if (tid < 256) dcb[tid] = 0.0f;
  __syncthreads();

  for (int c = 0; c < 8; ++c) {
    const int e = c * 256 + 256;
    const int bb = (e - 512 > 0) ? (e - 512) : 0;

    // ---- phase 1: LN(d_k) -> dknT + snapshot; v_state -> snapshot; ck0 -> ck0T
    for (int i0 = 0; i0 < 32; i0 += 4) {
      const int r0 = (w << 5) + i0;
      float kd[4], kn[4];
#pragma unroll
      for (int u = 0; u < 4; ++u) kd[u] = dkb[(r0 + u) * 64 + lane];
#pragma unroll
      for (int u = 0; u < 4; ++u) {
        float mean = waveSum(kd[u]) * (1.0f / 64.0f);
        float d0 = kd[u] - mean;
        float var = waveSum(d0 * d0) * (1.0f / 64.0f);
        kn[u] = d0 * rsqrtf(var + 1e-5f) * lw + lb;
      }
#pragma unroll
      for (int u = 0; u < 4; ++u) {
        dknT[lane][r0 + u] = kn[u];
        dksn[(size_t)c * 16384 + (r0 + u) * 64 + lane] = kn[u];
      }
    }
    for (int i0 = 0; i0 < 32; i0 += 4) {
      const int r0 = (w << 5) + i0;
      float vd[4];
#pragma unroll
      for (int u = 0; u < 4; ++u) vd[u] = dvb[(r0 + u) * 64 + lane];
#pragma unroll
      for (int u = 0; u < 4; ++u) {
        float nrm = fmaxf(sqrtf(waveSum(vd[u] * vd[u])), 1e-12f);
        vssn[(size_t)c * 16384 + (r0 + u) * 64 + lane] = vd[u] / nrm * dcb[r0 + u];
      }
    }
    for (int i0 = 0; i0 < 32; i0 += 4) {
      const int r0 = (w << 5) + i0;
      float kv[4];
#pragma unroll
      for (int u = 0; u < 4; ++u)
        kv[u] = (lane < 32) ? 0.0f : kb_[(size_t)(bb + r0 + u) * 64 + lane];
#pragma unroll
      for (int u = 0; u < 4; ++u) {
        float mean = waveSum(kv[u]) * (1.0f / 64.0f);
        float d0 = kv[u] - mean;
        float var = waveSum(d0 * d0) * (1.0f / 64.0f);
        ck0T[lane][r0 + u] = d0 * rsqrtf(var + 1e-5f) * lw + lb;
        if (lane == 0) kwc_s[r0 + u] = kwb[bb + r0 + u];
      }
    }
    __syncthreads();

    // ---- phase 2: sim (8rc x 8slot register tile) + fused argmax
    {
      const int tx = tid & 31, ty = tid >> 5;
#pragma unroll
      for (int pass = 0; pass < 2; ++pass) {
        const int rc0 = pass * 128 + ty * 8;
        float acc[8][8];
#pragma unroll
        for (int i = 0; i < 8; ++i)
#pragma unroll
          for (int j = 0; j < 8; ++j) acc[i][j] = 0.0f;
        for (int k = 0; k < 64; ++k) {
          float4 a0 = *(const float4*)&ck0T[k][rc0];
          float4 a1 = *(const float4*)&ck0T[k][rc0 + 4];
          float4 b0 = *(const float4*)&dknT[k][tx * 4];
          float4 b1 = *(const float4*)&dknT[k][tx * 4 + 128];
          float av[8] = {a0.x, a0.y, a0.z, a0.w, a1.x, a1.y, a1.z, a1.w};
          float bv[8] = {b0.x, b0.y, b0.z, b0.w, b1.x, b1.y, b1.z, b1.w};
#pragma unroll
          for (int i = 0; i < 8; ++i)
#pragma unroll
            for (int j = 0; j < 8; ++j) acc[i][j] += av[i] * bv[j];
        }
#pragma unroll
        for (int i = 0; i < 8; ++i) {
          float bv = -3.0e38f;
          int bi = 1 << 30;
#pragma unroll
          for (int j = 0; j < 8; ++j) {
            const int s = (j < 4) ? (tx * 4 + j) : (128 + tx * 4 + (j - 4));
            float vsc = acc[i][j];
            if (s == 0) vsc = -1.0e30f;  // SINK
            if (vsc > bv || (vsc == bv && s < bi)) { bv = vsc; bi = s; }
          }
#pragma unroll
          for (int o = 16; o; o >>= 1) {
            float ov = __shfl_xor(bv, o);
            int oi = __shfl_xor(bi, o);
            if (ov > bv || (ov == bv && oi < bi)) { bv = ov; bi = oi; }
          }
          if (tx == 0) best_s[rc0 + i] = bi;
        }
      }
    }
    __syncthreads();

    // ---- phase 3a: stage V window transposed into dknT (dead after sim)
    for (int i0 = 0; i0 < 32; i0 += 4) {
      const int r0 = (w << 5) + i0;
#pragma unroll
      for (int u = 0; u < 4; ++u)
        dknT[lane][r0 + u] = vb_[(size_t)(bb + r0 + u) * 64 + lane];
    }
    __syncthreads();

    // ---- phase 3b: scatter with register accumulation; thread=(slot,half)
    {
      const int s = tid >> 1, half = tid & 1;
      float accK[32], accV[32];
#pragma unroll
      for (int i2 = 0; i2 < 32; ++i2) { accK[i2] = 0.0f; accV[i2] = 0.0f; }
      int cnt = 0;
      for (int rc = 0; rc < 256; ++rc) {
        if (best_s[rc] == s) {
          const float kwv = kwc_s[rc];
#pragma unroll
          for (int i2 = 0; i2 < 32; ++i2) {
            accK[i2] += ck0T[half * 32 + i2][rc] * kwv;
            accV[i2] += dknT[half * 32 + i2][rc] * kwv;
          }
          ++cnt;
        }
      }
      if (cnt) {
        float* kp = dkb + s * 64 + half * 32;
        float* vp = dvb + s * 64 + half * 32;
#pragma unroll
        for (int i2 = 0; i2 < 32; ++i2) { kp[i2] += accK[i2]; vp[i2] += accV[i2]; }
        if (half == 0) dcb[s] += (float)cnt;
      }
    }
    __syncthreads();
  }
}

// Phase B: parallel attention. Grid 512 = (bh, chunk); thread owns one q-row.
__global__ __launch_bounds__(256) void attn_apply_kernel(
    const float* __restrict__ qf, const float* __restrict__ kfin,
    const float* __restrict__ vfin, const float* __restrict__ dkn_snap,
    const float* __restrict__ vst_snap, float* __restrict__ y,
    const float* __restrict__ ftp, const float* __restrict__ stp)
{
  const int blk = blockIdx.x;
  const int bh = blk >> 3;
  const int c = blk & 7;
  const int h = bh & (Hq - 1);
  const int tid = threadIdx.x;
  const size_t seq = (size_t)Tq * Nq;
  const int qi = c * 256 + tid;
  const int e = c * 256 + 256;
  const int bb = (e - 512 > 0) ? (e - 512) : 0;
  const int L = e - bb;
  const int ntile = 4 + (L >> 6);
  const float stsc = stp[h] * 0.125f, ftsc = ftp[h] * 0.125f;

  __shared__ float Ks[4096];
  __shared__ float Vs[4096];

  float q[64], o[64];
  {
    const float* qrow = qf + (size_t)bh * seq + (size_t)qi * 64;
#pragma unroll
    for (int d4 = 0; d4 < 16; ++d4) {
      float4 t = *(const float4*)(qrow + d4 * 4);
      q[4 * d4 + 0] = t.x; q[4 * d4 + 1] = t.y;
      q[4 * d4 + 2] = t.z; q[4 * d4 + 3] = t.w;
      o[4 * d4 + 0] = 0.f; o[4 * d4 + 1] = 0.f;
      o[4 * d4 + 2] = 0.f; o[4 * d4 + 3] = 0.f;
    }
  }
  float m = -3.0e38f, l = 0.0f;

  const float* kwin = kfin + (size_t)bh * seq;
  const float* vwin = vfin + (size_t)bh * seq;
  const float* dks = dkn_snap + ((size_t)(bh * 8 + c)) * 16384;
  const float* vss = vst_snap + ((size_t)(bh * 8 + c)) * 16384;

  for (int tt = 0; tt < ntile; ++tt) {
    const float* ksrc; const float* vsrc;
    int kt0 = 0;
    if (tt < 4) {
      ksrc = dks + tt * 4096;
      vsrc = vss + tt * 4096;
    } else {
      kt0 = bb + ((tt - 4) << 6);
      ksrc = kwin + (size_t)kt0 * 64;
      vsrc = vwin + (size_t)kt0 * 64;
    }
    __syncthreads();
#pragma unroll
    for (int i = 0; i < 4; ++i) {
      ((float4*)Ks)[i * 256 + tid] = ((const float4*)ksrc)[i * 256 + tid];
      ((float4*)Vs)[i * 256 + tid] = ((const float4*)vsrc)[i * 256 + tid];
    }
    __syncthreads();
    const float scale = (tt < 4) ? stsc : ftsc;
    int jmax = 64;
    if (tt >= 4) {
      int lim = qi - kt0 + 1;
      jmax = lim < 0 ? 0 : (lim > 64 ? 64 : lim);
    }
    for (int j = 0; j < jmax; ++j) {
      const float* kr = Ks + j * 64;
      float s = 0.0f;
#pragma unroll
      for (int d4 = 0; d4 < 16; ++d4) {
        float4 kv = *(const float4*)(kr + d4 * 4);
        s += q[4 * d4 + 0] * kv.x + q[4 * d4 + 1] * kv.y +
             q[4 * d4 + 2] * kv.z + q[4 * d4 + 3] * kv.w;
      }
      s *= scale;
      const float* vr = Vs + j * 64;
      if (s > m) {
        float al = __expf(m - s);
        m = s;
        l = l * al + 1.0f;
#pragma unroll
        for (int d4 = 0; d4 < 16; ++d4) {
          float4 vv = *(const float4*)(vr + d4 * 4);
          o[4 * d4 + 0] = o[4 * d4 + 0] * al + vv.x;
          o[4 * d4 + 1] = o[4 * d4 + 1] * al + vv.y;
          o[4 * d4 + 2] = o[4 * d4 + 2] * al + vv.z;
          o[4 * d4 + 3] = o[4 * d4 + 3] * al + vv.w;
        }
      } else {
        float p = __expf(s - m);
        l += p;
#pragma unroll
        for (int d4 = 0; d4 < 16; ++d4) {
          float4 vv = *(const float4*)(vr + d4 * 4);
          o[4 * d4 + 0] += p * vv.x;
          o[4 * d4 + 1] += p * vv.y;
          o[4 * d4 + 2] += p * vv.z;
          o[4 * d4 + 3] += p * vv.w;
        }
      }
    }
  }
  const float inv = 1.0f / l;
  float* yb = y + (size_t)bh * seq + (size_t)qi * 64;
#pragma unroll
  for (int d4 = 0; d4 < 16; ++d4) {
    float4 st4 = make_float4(o[4 * d4 + 0] * inv, o[4 * d4 + 1] * inv,
                             o[4 * d4 + 2] * inv, o[4 * d4 + 3] * inv);
    *(float4*)(yb + d4 * 4) = st4;
  }
}

// LN over C=1024 per (b,t); gathers from (B,H,T,N), writes (B,T,C)
__global__ __launch_bounds__(256) void final_ln(
    const float* __restrict__ y, const float* __restrict__ lnw,
    const float* __restrict__ lnb, float* __restrict__ dst)
{
  const int bt = blockIdx.x;
  const int b = bt >> 11, t = bt & (Tq - 1);
  const int tid = threadIdx.x, w = tid >> 6, lane = tid & 63;
  __shared__ float red[8];
  float v[4];
  float s = 0.0f;
#pragma unroll
  for (int i = 0; i < 4; ++i) {
    int c = tid + (i << 8);
    int h = c >> 6, n = c & 63;
    v[i] = y[((((size_t)b * Hq + h) * Tq + t) << 6) + n];
    s += v[i];
  }
  s = waveSum(s);
  if (lane == 0) red[w] = s;
  __syncthreads();
  const float mean = (red[0] + red[1] + red[2] + red[3]) * (1.0f / 1024.0f);
  float s2 = 0.0f;
#pragma unroll
  for (int i = 0; i < 4; ++i) { float d = v[i] - mean; s2 += d * d; }
  s2 = waveSum(s2);
  if (lane == 0) red[4 + w] = s2;
  __syncthreads();
  const float var = (red[4] + red[5] + red[6] + red[7]) * (1.0f / 1024.0f);
  const float rs = rsqrtf(var + 1e-5f);
#pragma unroll
  for (int i = 0; i < 4; ++i) {
    int c = tid + (i << 8);
    dst[(size_t)bt * Cq + c] = (v[i] - mean) * rs * lnw[c] + lnb[c];
  }
}

extern "C" void kernel_launch(void* const* d_in, const int* in_sizes, int n_in,
                              void* d_out, int out_size, void* d_ws, size_t ws_size,
                              hipStream_t stream)
{
  (void)in_sizes; (void)n_in; (void)out_size; (void)ws_size;
  const float* residual = (const float*)d_in[0];
  const float* x        = (const float*)d_in[1];
  const float* v1       = (const float*)d_in[2];
  const float* Wq       = (const float*)d_in[6];
  const float* Wk       = (const float*)d_in[7];
  const float* Wv       = (const float*)d_in[8];
  const float* Wproj    = (const float*)d_in[9];
  const float* Wkw      = (const float*)d_in[10];
  const float* x_q      = (const float*)d_in[11];
  const float* x_k      = (const float*)d_in[12];
  const float* x_v      = (const float*)d_in[13];
  const float* lamb     = (const float*)d_in[14];
  const float* ln_q_w   = (const float*)d_in[15];
  const float* ln_q_b   = (const float*)d_in[16];
  const float* ln_k_w   = (const float*)d_in[17];
  const float* ln_k_b   = (const float*)d_in[18];
  const float* ln_dk_w  = (const float*)d_in[19];
  const float* ln_dk_b  = (const float*)d_in[20];
  const float* ln_res_w = (const float*)d_in[21];
  const float* ln_res_b = (const float*)d_in[22];
  const float* ftp      = (const float*)d_in[23];
  const float* stp      = (const float*)d_in[24];

  float* ws = (float*)d_ws;
  const size_t SZ = (size_t)Bq * Hq * Tq * Nq;  // 8388608
  float* q_raw = ws;
  float* k_raw = ws + SZ;
  float* v_mix = ws + 2 * SZ;
  float* q_fin = ws + 3 * SZ;
  float* k_fin = ws + 4 * SZ;
  float* v_fin = ws + 5 * SZ;
  float* kwbuf = ws + 6 * SZ;                       // B*H*T = 131072
  float* dk = kwbuf + (size_t)Bq * Hq * Tq;         // 64*16384
  float* dv = dk + (size_t)Bq * Hq * 256 * 64;
  float* dc = dv + (size_t)Bq * Hq * 256 * 64;      // 64*256
  // snapshots reuse q_raw/k_raw (dead after postproc); 64*8*16384 == SZ exactly
  float* dkn_snap = q_raw;
  float* vst_snap = k_raw;
  float* ybuf = v_mix;   // v_mix dead after postproc
  float* ylnb = q_raw;   // dkn_snap dead after attn_apply

  dim3 gg(128, 16), gb(256);
  hipLaunchKernelGGL(gemm_nt, gg, gb, 0, stream, x, Wq, q_raw, (const float*)nullptr, lamb, 1);
  hipLaunchKernelGGL(gemm_nt, gg, gb, 0, stream, x, Wk, k_raw, (const float*)nullptr, lamb, 1);
  hipLaunchKernelGGL(gemm_nt, gg, gb, 0, stream, x, Wv, v_mix, v1, lamb, 2);
  hipLaunchKernelGGL(kw_kernel, dim3(Bq * Tq), gb, 0, stream, x, Wkw, kwbuf);
  const int rows = Bq * Hq * Tq;
  hipLaunchKernelGGL(postproc, dim3(rows / 4), gb, 0, stream, q_raw, q_fin, ln_q_w, ln_q_b, x_q, 1);
  hipLaunchKernelGGL(postproc, dim3(rows / 4), gb, 0, stream, k_raw, k_fin, ln_k_w, ln_k_b, x_k, 1);
  hipLaunchKernelGGL(postproc, dim3(rows / 4), gb, 0, stream, v_mix, v_fin, (const float*)nullptr, (const float*)nullptr, x_v, 0);
  hipLaunchKernelGGL(state_evolve_kernel, dim3(Bq * Hq), dim3(512), 0, stream,
                     k_fin, v_fin, kwbuf, dk, dv, dc, dkn_snap, vst_snap, ln_dk_w, ln_dk_b);
  hipLaunchKernelGGL(attn_apply_kernel, dim3(Bq * Hq * 8), gb, 0, stream,
                     q_fin, k_fin, v_fin, dkn_snap, vst_snap, ybuf, ftp, stp);
  hipLaunchKernelGGL(final_ln, dim3(Bq * Tq), gb, 0, stream, ybuf, ln_res_w, ln_res_b, ylnb);
  hipLaunchKernelGGL(gemm_nt, gg, gb, 0, stream, ylnb, Wproj, (float*)d_out, residual, lamb, 3);
}

// Round 4
// 2921.854 us; speedup vs baseline: 13.6964x; 1.2633x over previous
//
#include <hip/hip_runtime.h>
#include <math.h>

#define Bq 4
#define Tq 2048
#define Cq 1024
#define Hq 16
#define Nq 64

typedef __attribute__((ext_vector_type(8))) short short8v;
typedef __attribute__((ext_vector_type(4))) float f32x4;

__device__ inline float waveSum(float v) {
#pragma unroll
  for (int o = 32; o; o >>= 1) v += __shfl_xor(v, o);
  return v;
}
__device__ inline float sum16(float v) {
  v += __shfl_xor(v, 1);
  v += __shfl_xor(v, 2);
  v += __shfl_xor(v, 4);
  v += __shfl_xor(v, 8);
  return v;
}
__device__ inline unsigned short f2bf(float f) {
  unsigned u = __float_as_uint(f);
  unsigned r = (u + 0x7FFFu + ((u >> 16) & 1u)) >> 16;
  return (unsigned short)r;
}

__global__ __launch_bounds__(256) void f32_to_bf16_kernel(
    const float* __restrict__ src, unsigned short* __restrict__ dst, int n4)
{
  int i = blockIdx.x * 256 + threadIdx.x;
  if (i >= n4) return;
  float4 v = ((const float4*)src)[i];
  ushort4 o;
  o.x = f2bf(v.x); o.y = f2bf(v.y); o.z = f2bf(v.z); o.w = f2bf(v.w);
  ((ushort4*)dst)[i] = o;
}

// ---- f32 GEMM (kept for K path only; precision-critical for argmax) ----
__global__ __launch_bounds__(256) void gemm_nt(
    const float* __restrict__ A, const float* __restrict__ W,
    float* __restrict__ dst, const float* __restrict__ extra,
    const float* __restrict__ lamb_p, int mode)
{
  const int K = Cq;
  const int m0 = blockIdx.x * 64, j0 = blockIdx.y * 64;
  __shared__ float As[16][65];
  __shared__ float Bs[16][65];
  const int tid = threadIdx.x;
  const int tx = tid & 15, ty = tid >> 4;
  float acc[4][4] = {{0.f}};
  for (int k0 = 0; k0 < K; k0 += 16) {
#pragma unroll
    for (int i = 0; i < 4; ++i) {
      int idx = tid + i * 256;
      int mm = idx >> 4, kk = idx & 15;
      As[kk][mm] = A[(size_t)(m0 + mm) * K + k0 + kk];
      Bs[kk][mm] = W[(size_t)(j0 + mm) * K + k0 + kk];
    }
    __syncthreads();
#pragma unroll
    for (int k = 0; k < 16; ++k) {
      float a4[4], b4[4];
#pragma unroll
      for (int i = 0; i < 4; ++i) a4[i] = As[k][ty * 4 + i];
#pragma unroll
      for (int j = 0; j < 4; ++j) b4[j] = Bs[k][tx * 4 + j];
#pragma unroll
      for (int i = 0; i < 4; ++i)
#pragma unroll
        for (int j = 0; j < 4; ++j) acc[i][j] += a4[i] * b4[j];
    }
    __syncthreads();
  }
  const float lam = (mode == 2) ? lamb_p[0] : 0.0f;
#pragma unroll
  for (int i = 0; i < 4; ++i) {
    int m = m0 + ty * 4 + i;
#pragma unroll
    for (int j = 0; j < 4; ++j) {
      int jj = j0 + tx * 4 + j;
      float v = acc[i][j];
      if (mode == 3) {
        dst[(size_t)m * Cq + jj] = v + extra[(size_t)m * Cq + jj];
      } else {
        if (mode == 2) v = (1.0f - lam) * v + lam * extra[(size_t)m * Cq + jj];
        int b = m >> 11, t = m & (Tq - 1);
        int h = jj >> 6, n = jj & 63;
        dst[((((size_t)b * Hq + h) * Tq + t) << 6) | n] = v;
      }
    }
  }
}

// ---- bf16 MFMA GEMM: C[m][n] = sum_k A[m][k]*W[n][k], K=1024 ----
// 128x128 tile, 4 waves (2x2 of 64x64), direct-global fragment loads.
__global__ __launch_bounds__(256) void gemm_bf16(
    const unsigned short* __restrict__ A, const unsigned short* __restrict__ W,
    float* __restrict__ dst, const float* __restrict__ extra,
    const float* __restrict__ lamb_p, int mode)
{
  const int m0 = blockIdx.x * 128, n0 = blockIdx.y * 128;
  const int tid = threadIdx.x;
  const int w = tid >> 6, l = tid & 63;
  const int wr = w >> 1, wc = w & 1;
  const int lrow = l & 15;
  const int lk = (l >> 4) * 8;

  f32x4 acc[4][4];
#pragma unroll
  for (int i = 0; i < 4; ++i)
#pragma unroll
    for (int j = 0; j < 4; ++j) acc[i][j] = (f32x4){0.f, 0.f, 0.f, 0.f};

  const unsigned short* Ab = A + (((size_t)(m0 + wr * 64 + lrow)) << 10) + lk;
  const unsigned short* Wb = W + (((size_t)(n0 + wc * 64 + lrow)) << 10) + lk;

  for (int k0 = 0; k0 < 1024; k0 += 32) {
    short8v a[4], b[4];
#pragma unroll
    for (int i = 0; i < 4; ++i) a[i] = *(const short8v*)(Ab + (((size_t)i) << 14) + k0);
#pragma unroll
    for (int j = 0; j < 4; ++j) b[j] = *(const short8v*)(Wb + (((size_t)j) << 14) + k0);
#pragma unroll
    for (int i = 0; i < 4; ++i)
#pragma unroll
      for (int j = 0; j < 4; ++j)
        acc[i][j] = __builtin_amdgcn_mfma_f32_16x16x32_bf16(a[i], b[j], acc[i][j], 0, 0, 0);
  }

  const float lam = (mode == 2) ? lamb_p[0] : 0.0f;
#pragma unroll
  for (int i = 0; i < 4; ++i)
#pragma unroll
    for (int j = 0; j < 4; ++j)
#pragma unroll
      for (int rg = 0; rg < 4; ++rg) {
        int m = m0 + wr * 64 + i * 16 + (l >> 4) * 4 + rg;
        int n = n0 + wc * 64 + j * 16 + (l & 15);
        float v = acc[i][j][rg];
        if (mode == 3) {
          dst[(size_t)m * Cq + n] = v + extra[(size_t)m * Cq + n];
        } else {
          if (mode == 2) v = (1.0f - lam) * v + lam * extra[(size_t)m * Cq + n];
          int b = m >> 11, t = m & (Tq - 1);
          int h = n >> 6, nn = n & 63;
          dst[((((size_t)b * Hq + h) * Tq + t) << 6) | nn] = v;
        }
      }
}

// LN (optional) + token-shift blend + RoPE (optional). src/dst in (B,H,T,N).
__global__ __launch_bounds__(256) void postproc(
    const float* __restrict__ src, float* __restrict__ dst,
    const float* __restrict__ lnw, const float* __restrict__ lnb,
    const float* __restrict__ xs_p, int doLNRope)
{
  const int w = threadIdx.x >> 6, lane = threadIdx.x & 63;
  const int row = blockIdx.x * 4 + w;
  const int t = row & (Tq - 1);
  const int h = (row >> 11) & (Hq - 1);
  const size_t base = (size_t)row << 6;
  const size_t pbase = (t > 0) ? base - 64 : base;
  float cur = src[base + lane];
  float prv = src[pbase + lane];
  if (doLNRope) {
    const float lw = lnw[lane], lb = lnb[lane];
    {
      float m = waveSum(cur) * (1.0f / 64.0f);
      float d = cur - m;
      float var = waveSum(d * d) * (1.0f / 64.0f);
      cur = d * rsqrtf(var + 1e-5f) * lw + lb;
    }
    {
      float m = waveSum(prv) * (1.0f / 64.0f);
      float d = prv - m;
      float var = waveSum(d * d) * (1.0f / 64.0f);
      prv = d * rsqrtf(var + 1e-5f) * lw + lb;
    }
  }
  const float xv = xs_p[h * 64 + lane];
  float val = cur + xv * (prv - cur);
  if (doLNRope) {
    float partner = __shfl_xor(val, 1);
    if (lane < 32) {
      int i = lane >> 1;
      float freq = (float)exp((double)i * (-log(10000.0) / 15.0));
      float th = (float)t * freq;
      float c = cosf(th), s = sinf(th);
      val = c * val + ((lane & 1) ? -s : s) * partner;
    }
  }
  dst[base + lane] = val;
}

__global__ __launch_bounds__(256) void kw_kernel(
    const float* __restrict__ x, const float* __restrict__ Wkw, float* __restrict__ out)
{
  const int bt = blockIdx.x;
  const int tid = threadIdx.x, w = tid >> 6, lane = tid & 63;
  __shared__ float xs[Cq];
  for (int i = tid; i < Cq; i += 256) xs[i] = x[(size_t)bt * Cq + i];
  __syncthreads();
  const int b = bt >> 11, t = bt & (Tq - 1);
  for (int h = w; h < Hq; h += 4) {
    float acc = 0.0f;
    for (int i = lane; i < Cq; i += 64) acc += xs[i] * Wkw[h * Cq + i];
    acc = waveSum(acc);
    if (lane == 0) out[((size_t)(b * Hq + h)) * Tq + t] = 1.0f / (1.0f + expf(-acc));
  }
}

// Phase A: sequential state evolution per (b,h); 64 blocks x 1024 threads.
// Rotated LDS layout phys(r,d) = r*68 + ((d+r)&63): conflict-free writes,
// conflict-free phase-2 column reads (bank = (5tx+k)%32, gcd(5,32)=1).
__global__ __launch_bounds__(1024, 4) void state_evolve_kernel(
    const float* __restrict__ kf, const float* __restrict__ vf,
    const float* __restrict__ kwp,
    float* __restrict__ dkg, float* __restrict__ dvg,
    float* __restrict__ dkn_snap, float* __restrict__ vst_snap,
    const float* __restrict__ lnw, const float* __restrict__ lnb)
{
  const int bh = blockIdx.x;
  const int tid = threadIdx.x;
  const int w2 = tid >> 6, l = tid & 63;
  const int lr = l >> 4, lc = l & 15;
  const int d0 = lc * 4;
  const size_t seq = (size_t)Tq * Nq;
  const float* kb_ = kf + (size_t)bh * seq;
  const float* vb_ = vf + (size_t)bh * seq;
  const float* kwb = kwp + (size_t)bh * Tq;
  float* dkb = dkg + (size_t)bh * (256 * 64);
  float* dvb = dvg + (size_t)bh * (256 * 64);
  float* dksn = dkn_snap + (size_t)bh * 8 * 16384;
  float* vssn = vst_snap + (size_t)bh * 8 * 16384;
  const float4 lw4 = *(const float4*)(lnw + d0);
  const float4 lb4 = *(const float4*)(lnb + d0);

  __shared__ float dknR[256 * 68];  // rotated; reused as V-window in 3a/3b
  __shared__ float ck0R[256 * 68];  // rotated
  __shared__ float kwc_s[256];
  __shared__ float dcs[256];
  __shared__ int best_s[256];

  for (int i = tid; i < 256 * 64; i += 1024) { dkb[i] = 0.0f; dvb[i] = 0.0f; }
  if (tid < 256) dcs[tid] = 0.0f;
  __syncthreads();

  for (int c = 0; c < 8; ++c) {
    const int e = c * 256 + 256;
    const int bb = (e - 512 > 0) ? (e - 512) : 0;

    // ---- phase 1: per wave 16 rows, 4 rows per step (16 lanes x float4 each)
#pragma unroll
    for (int step = 0; step < 4; ++step) {
      const int r = w2 * 16 + step * 4 + lr;
      const int rb = r * 68;
      // dkn = LN(d_k): LDS(rotated) + snapshot
      {
        float4 kd = *(const float4*)(dkb + r * 64 + d0);
        float mean = sum16(kd.x + kd.y + kd.z + kd.w) * (1.0f / 64.0f);
        float dx = kd.x - mean, dy = kd.y - mean, dz = kd.z - mean, dw = kd.w - mean;
        float var = sum16(dx * dx + dy * dy + dz * dz + dw * dw) * (1.0f / 64.0f);
        float rs = rsqrtf(var + 1e-5f);
        float4 kn = make_float4(dx * rs * lw4.x + lb4.x, dy * rs * lw4.y + lb4.y,
                                dz * rs * lw4.z + lb4.z, dw * rs * lw4.w + lb4.w);
        dknR[rb + ((d0 + 0 + r) & 63)] = kn.x;
        dknR[rb + ((d0 + 1 + r) & 63)] = kn.y;
        dknR[rb + ((d0 + 2 + r) & 63)] = kn.z;
        dknR[rb + ((d0 + 3 + r) & 63)] = kn.w;
        *(float4*)(dksn + (size_t)c * 16384 + r * 64 + d0) = kn;
      }
      // v_state snapshot
      {
        float4 vd = *(const float4*)(dvb + r * 64 + d0);
        float nq = sum16(vd.x * vd.x + vd.y * vd.y + vd.z * vd.z + vd.w * vd.w);
        float nrm = fmaxf(sqrtf(nq), 1e-12f);
        float sc = dcs[r] / nrm;
        *(float4*)(vssn + (size_t)c * 16384 + r * 64 + d0) =
            make_float4(vd.x * sc, vd.y * sc, vd.z * sc, vd.w * sc);
      }
      // ck0 = LN(zero-first-32(c_k)) -> rotated LDS
      {
        float4 kv = make_float4(0.f, 0.f, 0.f, 0.f);
        if (d0 >= 32) kv = *(const float4*)(kb_ + (size_t)(bb + r) * 64 + d0);
        float mean = sum16(kv.x + kv.y + kv.z + kv.w) * (1.0f / 64.0f);
        float dx = kv.x - mean, dy = kv.y - mean, dz = kv.z - mean, dw = kv.w - mean;
        float var = sum16(dx * dx + dy * dy + dz * dz + dw * dw) * (1.0f / 64.0f);
        float rs = rsqrtf(var + 1e-5f);
        ck0R[rb + ((d0 + 0 + r) & 63)] = dx * rs * lw4.x + lb4.x;
        ck0R[rb + ((d0 + 1 + r) & 63)] = dy * rs * lw4.y + lb4.y;
        ck0R[rb + ((d0 + 2 + r) & 63)] = dz * rs * lw4.z + lb4.z;
        ck0R[rb + ((d0 + 3 + r) & 63)] = dw * rs * lw4.w + lb4.w;
        if (lc == 0) kwc_s[r] = kwb[bb + r];
      }
    }
    __syncthreads();

    // ---- phase 2: sim + fused argmax. thread = (ty: 8 rc rows, tx: 8 slots stride 32)
    {
      const int ty = tid >> 5, tx = tid & 31;
      const int rc0 = ty * 8;
      float acc[8][8];
#pragma unroll
      for (int i = 0; i < 8; ++i)
#pragma unroll
        for (int j = 0; j < 8; ++j) acc[i][j] = 0.0f;
      for (int k = 0; k < 64; ++k) {
        float av[8], bv[8];
#pragma unroll
        for (int i = 0; i < 8; ++i)
          av[i] = ck0R[(rc0 + i) * 68 + ((k + rc0 + i) & 63)];
#pragma unroll
        for (int j = 0; j < 8; ++j) {
          int s = tx + 32 * j;
          bv[j] = dknR[s * 68 + ((k + s) & 63)];
        }
#pragma unroll
        for (int i = 0; i < 8; ++i)
#pragma unroll
          for (int j = 0; j < 8; ++j) acc[i][j] += av[i] * bv[j];
      }
#pragma unroll
      for (int i = 0; i < 8; ++i) {
        float bvv = -3.0e38f;
        int bi = 1 << 30;
#pragma unroll
        for (int j = 0; j < 8; ++j) {
          int s = tx + 32 * j;
          float v = acc[i][j];
          if (s == 0) v = -1.0e30f;  // SINK
          if (v > bvv || (v == bvv && s < bi)) { bvv = v; bi = s; }
        }
#pragma unroll
        for (int o = 16; o; o >>= 1) {
          float ov = __shfl_xor(bvv, o);
          int oi = __shfl_xor(bi, o);
          if (ov > bvv || (ov == bvv && oi < bi)) { bvv = ov; bi = oi; }
        }
        if (tx == 0) best_s[rc0 + i] = bi;
      }
    }
    __syncthreads();

    // ---- phase 3a: stage V window into dknR (rotated), dead after sim
#pragma unroll
    for (int step = 0; step < 4; ++step) {
      const int r = w2 * 16 + step * 4 + lr;
      float4 vv = *(const float4*)(vb_ + (size_t)(bb + r) * 64 + d0);
      dknR[r * 68 + ((d0 + 0 + r) & 63)] = vv.x;
      dknR[r * 68 + ((d0 + 1 + r) & 63)] = vv.y;
      dknR[r * 68 + ((d0 + 2 + r) & 63)] = vv.z;
      dknR[r * 68 + ((d0 + 3 + r) & 63)] = vv.w;
    }
    __syncthreads();

    // ---- phase 3b: scatter; thread = (slot, quarter of dims)
    {
      const int s = tid >> 2, qd = tid & 3;
      const int db = qd * 16;
      float accK[16], accV[16];
#pragma unroll
      for (int i2 = 0; i2 < 16; ++i2) { accK[i2] = 0.0f; accV[i2] = 0.0f; }
      int cnt = 0;
      for (int rc = 0; rc < 256; ++rc) {
        if (best_s[rc] == s) {
          const float kwv = kwc_s[rc];
          const int rb = rc * 68;
#pragma unroll
          for (int i2 = 0; i2 < 16; ++i2) {
            int off = rb + ((db + i2 + rc) & 63);
            accK[i2] += ck0R[off] * kwv;
            accV[i2] += dknR[off] * kwv;
          }
          ++cnt;
        }
      }
      if (cnt) {
        float* kp = dkb + s * 64 + db;
        float* vp = dvb + s * 64 + db;
#pragma unroll
        for (int i2 = 0; i2 < 16; ++i2) { kp[i2] += accK[i2]; vp[i2] += accV[i2]; }
        if (qd == 0) dcs[s] += (float)cnt;
      }
    }
    __syncthreads();
  }
}

// Phase B: parallel attention. Grid 512 = (bh, chunk); thread owns one q-row.
__global__ __launch_bounds__(256) void attn_apply_kernel(
    const float* __restrict__ qf, const float* __restrict__ kfin,
    const float* __restrict__ vfin, const float* __restrict__ dkn_snap,
    const float* __restrict__ vst_snap, float* __restrict__ y,
    const float* __restrict__ ftp, const float* __restrict__ stp)
{
  const int blk = blockIdx.x;
  const int bh = blk >> 3;
  const int c = blk & 7;
  const int h = bh & (Hq - 1);
  const int tid = threadIdx.x;
  const size_t seq = (size_t)Tq * Nq;
  const int qi = c * 256 + tid;
  const int e = c * 256 + 256;
  const int bb = (e - 512 > 0) ? (e - 512) : 0;
  const int L = e - bb;
  const int ntile = 4 + (L >> 6);
  const float stsc = stp[h] * 0.125f, ftsc = ftp[h] * 0.125f;

  __shared__ float Ks[4096];
  __shared__ float Vs[4096];

  float q[64], o[64];
  {
    const float* qrow = qf + (size_t)bh * seq + (size_t)qi * 64;
#pragma unroll
    for (int d4 = 0; d4 < 16; ++d4) {
      float4 t = *(const float4*)(qrow + d4 * 4);
      q[4 * d4 + 0] = t.x; q[4 * d4 + 1] = t.y;
      q[4 * d4 + 2] = t.z; q[4 * d4 + 3] = t.w;
      o[4 * d4 + 0] = 0.f; o[4 * d4 + 1] = 0.f;
      o[4 * d4 + 2] = 0.f; o[4 * d4 + 3] = 0.f;
    }
  }
  float m = -3.0e38f, l = 0.0f;

  const float* kwin = kfin + (size_t)bh * seq;
  const float* vwin = vfin + (size_t)bh * seq;
  const float* dks = dkn_snap + ((size_t)(bh * 8 + c)) * 16384;
  const float* vss = vst_snap + ((size_t)(bh * 8 + c)) * 16384;

  for (int tt = 0; tt < ntile; ++tt) {
    const float* ksrc; const float* vsrc;
    int kt0 = 0;
    if (tt < 4) {
      ksrc = dks + tt * 4096;
      vsrc = vss + tt * 4096;
    } else {
      kt0 = bb + ((tt - 4) << 6);
      ksrc = kwin + (size_t)kt0 * 64;
      vsrc = vwin + (size_t)kt0 * 64;
    }
    __syncthreads();
#pragma unroll
    for (int i = 0; i < 4; ++i) {
      ((float4*)Ks)[i * 256 + tid] = ((const float4*)ksrc)[i * 256 + tid];
      ((float4*)Vs)[i * 256 + tid] = ((const float4*)vsrc)[i * 256 + tid];
    }
    __syncthreads();
    const float scale = (tt < 4) ? stsc : ftsc;
    int jmax = 64;
    if (tt >= 4) {
      int lim = qi - kt0 + 1;
      jmax = lim < 0 ? 0 : (lim > 64 ? 64 : lim);
    }
    for (int j = 0; j < jmax; ++j) {
      const float* kr = Ks + j * 64;
      float s = 0.0f;
#pragma unroll
      for (int d4 = 0; d4 < 16; ++d4) {
        float4 kv = *(const float4*)(kr + d4 * 4);
        s += q[4 * d4 + 0] * kv.x + q[4 * d4 + 1] * kv.y +
             q[4 * d4 + 2] * kv.z + q[4 * d4 + 3] * kv.w;
      }
      s *= scale;
      const float* vr = Vs + j * 64;
      if (s > m) {
        float al = __expf(m - s);
        m = s;
        l = l * al + 1.0f;
#pragma unroll
        for (int d4 = 0; d4 < 16; ++d4) {
          float4 vv = *(const float4*)(vr + d4 * 4);
          o[4 * d4 + 0] = o[4 * d4 + 0] * al + vv.x;
          o[4 * d4 + 1] = o[4 * d4 + 1] * al + vv.y;
          o[4 * d4 + 2] = o[4 * d4 + 2] * al + vv.z;
          o[4 * d4 + 3] = o[4 * d4 + 3] * al + vv.w;
        }
      } else {
        float p = __expf(s - m);
        l += p;
#pragma unroll
        for (int d4 = 0; d4 < 16; ++d4) {
          float4 vv = *(const float4*)(vr + d4 * 4);
          o[4 * d4 + 0] += p * vv.x;
          o[4 * d4 + 1] += p * vv.y;
          o[4 * d4 + 2] += p * vv.z;
          o[4 * d4 + 3] += p * vv.w;
        }
      }
    }
  }
  const float inv = 1.0f / l;
  float* yb = y + (size_t)bh * seq + (size_t)qi * 64;
#pragma unroll
  for (int d4 = 0; d4 < 16; ++d4) {
    float4 st4 = make_float4(o[4 * d4 + 0] * inv, o[4 * d4 + 1] * inv,
                             o[4 * d4 + 2] * inv, o[4 * d4 + 3] * inv);
    *(float4*)(yb + d4 * 4) = st4;
  }
}

// LN over C=1024 per (b,t); gathers from (B,H,T,N), writes (B,T,C)
__global__ __launch_bounds__(256) void final_ln(
    const float* __restrict__ y, const float* __restrict__ lnw,
    const float* __restrict__ lnb, float* __restrict__ dst)
{
  const int bt = blockIdx.x;
  const int b = bt >> 11, t = bt & (Tq - 1);
  const int tid = threadIdx.x, w = tid >> 6, lane = tid & 63;
  __shared__ float red[8];
  float v[4];
  float s = 0.0f;
#pragma unroll
  for (int i = 0; i < 4; ++i) {
    int c = tid + (i << 8);
    int h = c >> 6, n = c & 63;
    v[i] = y[((((size_t)b * Hq + h) * Tq + t) << 6) + n];
    s += v[i];
  }
  s = waveSum(s);
  if (lane == 0) red[w] = s;
  __syncthreads();
  const float mean = (red[0] + red[1] + red[2] + red[3]) * (1.0f / 1024.0f);
  float s2 = 0.0f;
#pragma unroll
  for (int i = 0; i < 4; ++i) { float d = v[i] - mean; s2 += d * d; }
  s2 = waveSum(s2);
  if (lane == 0) red[4 + w] = s2;
  __syncthreads();
  const float var = (red[4] + red[5] + red[6] + red[7]) * (1.0f / 1024.0f);
  const float rs = rsqrtf(var + 1e-5f);
#pragma unroll
  for (int i = 0; i < 4; ++i) {
    int c = tid + (i << 8);
    dst[(size_t)bt * Cq + c] = (v[i] - mean) * rs * lnw[c] + lnb[c];
  }
}

extern "C" void kernel_launch(void* const* d_in, const int* in_sizes, int n_in,
                              void* d_out, int out_size, void* d_ws, size_t ws_size,
                              hipStream_t stream)
{
  (void)in_sizes; (void)n_in; (void)out_size; (void)ws_size;
  const float* residual = (const float*)d_in[0];
  const float* x        = (const float*)d_in[1];
  const float* v1       = (const float*)d_in[2];
  const float* Wq       = (const float*)d_in[6];
  const float* Wk       = (const float*)d_in[7];
  const float* Wv       = (const float*)d_in[8];
  const float* Wproj    = (const float*)d_in[9];
  const float* Wkw      = (const float*)d_in[10];
  const float* x_q      = (const float*)d_in[11];
  const float* x_k      = (const float*)d_in[12];
  const float* x_v      = (const float*)d_in[13];
  const float* lamb     = (const float*)d_in[14];
  const float* ln_q_w   = (const float*)d_in[15];
  const float* ln_q_b   = (const float*)d_in[16];
  const float* ln_k_w   = (const float*)d_in[17];
  const float* ln_k_b   = (const float*)d_in[18];
  const float* ln_dk_w  = (const float*)d_in[19];
  const float* ln_dk_b  = (const float*)d_in[20];
  const float* ln_res_w = (const float*)d_in[21];
  const float* ln_res_b = (const float*)d_in[22];
  const float* ftp      = (const float*)d_in[23];
  const float* stp      = (const float*)d_in[24];

  float* ws = (float*)d_ws;
  const size_t SZ = (size_t)Bq * Hq * Tq * Nq;  // 8388608
  float* q_raw = ws;
  float* k_raw = ws + SZ;
  float* v_mix = ws + 2 * SZ;
  float* q_fin = ws + 3 * SZ;
  float* k_fin = ws + 4 * SZ;
  float* v_fin = ws + 5 * SZ;
  float* kwbuf = ws + 6 * SZ;                       // B*H*T = 131072
  float* dk = kwbuf + (size_t)Bq * Hq * Tq;         // 64*16384
  float* dv = dk + (size_t)Bq * Hq * 256 * 64;
  // aliases (lifetime-disjoint):
  float* dkn_snap = q_raw;                // written by state_evolve after q_raw dead
  float* vst_snap = k_raw;
  float* ybuf = v_mix;                    // v_mix dead after postproc-v
  float* ylnb = q_raw;                    // dkn_snap dead after attn_apply
  unsigned short* xb  = (unsigned short*)q_fin;        // dead before postproc-q writes q_fin
  unsigned short* wqb = xb + SZ;
  unsigned short* wvb = wqb + (1u << 20);
  unsigned short* wpb = (unsigned short*)k_fin;        // k_fin dead after attn_apply
  unsigned short* ylnbb = (unsigned short*)v_fin;      // v_fin dead after attn_apply

  dim3 gb(256);
  dim3 ggf(128, 16);   // f32 gemm grid
  dim3 ggb(64, 8);     // bf16 gemm grid

  hipLaunchKernelGGL(f32_to_bf16_kernel, dim3((int)(SZ / 4 / 256)), gb, 0, stream, x, xb, (int)(SZ / 4));
  hipLaunchKernelGGL(f32_to_bf16_kernel, dim3(1024), gb, 0, stream, Wq, wqb, 262144);
  hipLaunchKernelGGL(f32_to_bf16_kernel, dim3(1024), gb, 0, stream, Wv, wvb, 262144);

  hipLaunchKernelGGL(gemm_bf16, ggb, gb, 0, stream, xb, wqb, q_raw, (const float*)nullptr, lamb, 1);
  hipLaunchKernelGGL(gemm_nt, ggf, gb, 0, stream, x, Wk, k_raw, (const float*)nullptr, lamb, 1);
  hipLaunchKernelGGL(gemm_bf16, ggb, gb, 0, stream, xb, wvb, v_mix, v1, lamb, 2);
  hipLaunchKernelGGL(kw_kernel, dim3(Bq * Tq), gb, 0, stream, x, Wkw, kwbuf);

  const int rows = Bq * Hq * Tq;
  hipLaunchKernelGGL(postproc, dim3(rows / 4), gb, 0, stream, q_raw, q_fin, ln_q_w, ln_q_b, x_q, 1);
  hipLaunchKernelGGL(postproc, dim3(rows / 4), gb, 0, stream, k_raw, k_fin, ln_k_w, ln_k_b, x_k, 1);
  hipLaunchKernelGGL(postproc, dim3(rows / 4), gb, 0, stream, v_mix, v_fin, (const float*)nullptr, (const float*)nullptr, x_v, 0);

  hipLaunchKernelGGL(state_evolve_kernel, dim3(Bq * Hq), dim3(1024), 0, stream,
                     k_fin, v_fin, kwbuf, dk, dv, dkn_snap, vst_snap, ln_dk_w, ln_dk_b);
  hipLaunchKernelGGL(attn_apply_kernel, dim3(Bq * Hq * 8), gb, 0, stream,
                     q_fin, k_fin, v_fin, dkn_snap, vst_snap, ybuf, ftp, stp);

  hipLaunchKernelGGL(f32_to_bf16_kernel, dim3(1024), gb, 0, stream, Wproj, wpb, 262144);
  hipLaunchKernelGGL(final_ln, dim3(Bq * Tq), gb, 0, stream, ybuf, ln_res_w, ln_res_b, ylnb);
  hipLaunchKernelGGL(f32_to_bf16_kernel, dim3((int)(SZ / 4 / 256)), gb, 0, stream, ylnb, ylnbb, (int)(SZ / 4));
  hipLaunchKernelGGL(gemm_bf16, ggb, gb, 0, stream, ylnbb, wpb, (float*)d_out, residual, lamb, 3);
}